// Round 2
// baseline (331.228 us; speedup 1.0000x reference)
//
#include <hip/hip_runtime.h>
#include <hip/hip_bf16.h>

#define VOCAB 64
#define H 64
#define NB 128
#define SL 2048

// ---------------- Kernel A: per-token tables ----------------
// grid 64 (token), block 64 (dim i). Entire encoder depends only on token id.
__global__ __launch_bounds__(64) void k_tables(
    const float* __restrict__ embed, const float* __restrict__ w1, const float* __restrict__ b1,
    const float* __restrict__ w2, const float* __restrict__ b2,
    const float* __restrict__ ln_g, const float* __restrict__ ln_b,
    const float* __restrict__ Wk, const float* __restrict__ Wv, const float* __restrict__ Wq,
    float* __restrict__ Ktab, float* __restrict__ Vtab, float* __restrict__ qtab)
{
  const int t = blockIdx.x;
  const int i = threadIdx.x;
  __shared__ float h0s[H];
  __shared__ float ff1s[2 * H];
  __shared__ float hs[H];

  h0s[i] = embed[t * H + i];
  __syncthreads();

  float a0 = b1[i], a1 = b1[i + H];
#pragma unroll
  for (int j = 0; j < H; ++j) {
    a0 = fmaf(w1[i * H + j], h0s[j], a0);
    a1 = fmaf(w1[(i + H) * H + j], h0s[j], a1);
  }
  ff1s[i] = fmaxf(a0, 0.f);
  ff1s[i + H] = fmaxf(a1, 0.f);
  __syncthreads();

  float z = h0s[i] + b2[i];
#pragma unroll
  for (int o = 0; o < 2 * H; ++o) z = fmaf(w2[i * 2 * H + o], ff1s[o], z);

  // LayerNorm across the 64 lanes (block == 1 wave)
  float s = z;
#pragma unroll
  for (int m = 1; m < 64; m <<= 1) s += __shfl_xor(s, m);
  const float mu = s * (1.f / 64.f);
  const float d = z - mu;
  float s2 = d * d;
#pragma unroll
  for (int m = 1; m < 64; m <<= 1) s2 += __shfl_xor(s2, m);
  const float var = s2 * (1.f / 64.f);
  const float hv = d * rsqrtf(var + 1e-5f) * ln_g[i] + ln_b[i];
  hs[i] = hv;
  __syncthreads();

  float kk = 0.f, vv = 0.f, qq = 0.f;
#pragma unroll
  for (int j = 0; j < H; ++j) {
    const float hj = hs[j];
    kk = fmaf(Wk[i * H + j], hj, kk);
    vv = fmaf(Wv[i * H + j], hj, vv);
    qq = fmaf(Wq[i * H + j], hj, qq);
  }
  float n2 = kk * kk;
#pragma unroll
  for (int m = 1; m < 64; m <<= 1) n2 += __shfl_xor(n2, m);
  const float inv = 1.f / fmaxf(sqrtf(n2), 1e-12f);
  Ktab[t * H + i] = kk * inv;
  Vtab[t * H + i] = vv;
  qtab[t * H + i] = qq;
}

// ---------------- Kernel A2: Gram matrix G[a][b] = k_a . k_b ----------------
__global__ __launch_bounds__(64) void k_gram(const float* __restrict__ Ktab,
                                             float* __restrict__ G)
{
  const int a = blockIdx.x;
  const int b = threadIdx.x;
  __shared__ float row[H];
  row[b] = Ktab[a * H + b];
  __syncthreads();
  float s = 0.f;
#pragma unroll
  for (int i = 0; i < H; ++i) s = fmaf(row[i], Ktab[b * H + i], s);
  G[a * VOCAB + b] = s;
}

// ---------------- Kernel B: chunked delta-rule scan ----------------
// Exact reorder of the serial delta rule using the token Gram matrix:
//   pre_t = M_pre . k_t                      (8 independent dot+reduce)
//   dl    = triangular solve with g[s][t]=G[x_s][x_t]  (short scalar chain)
//   M    += sum_t dl_t k_t^T                 (rank-8 update, independent)
template <int CTRL>
__device__ __forceinline__ float dpp_add(float x) {
  int y = __builtin_amdgcn_update_dpp(0, __float_as_int(x), CTRL, 0xF, 0xF, false);
  return x + __int_as_float(y);
}

__global__ __launch_bounds__(256) void k_scan(
    const int* __restrict__ x, const float* __restrict__ Ktab, const float* __restrict__ Vtab,
    const float* __restrict__ G, float* __restrict__ Mout)
{
  const int bb = blockIdx.x >> 1;
  const int half = blockIdx.x & 1;
  const int tid = threadIdx.x;

  __shared__ float Kt[VOCAB * H];
  __shared__ float Vt[VOCAB * H];
  __shared__ float Gl[VOCAB * VOCAB];
#pragma unroll
  for (int u = 0; u < 4; ++u) {
    ((float4*)Kt)[u * 256 + tid] = ((const float4*)Ktab)[u * 256 + tid];
    ((float4*)Vt)[u * 256 + tid] = ((const float4*)Vtab)[u * 256 + tid];
    ((float4*)Gl)[u * 256 + tid] = ((const float4*)G)[u * 256 + tid];
  }
  __syncthreads();

  const int r = half * 32 + (tid >> 3);
  const int c8 = (tid & 7) * 8;

  float M[8] = {0.f, 0.f, 0.f, 0.f, 0.f, 0.f, 0.f, 0.f};
  const int* __restrict__ xrow = x + bb * SL;

  for (int t0 = 0; t0 < SL; t0 += 8) {
    int tk[8];
#pragma unroll
    for (int u = 0; u < 8; ++u) tk[u] = __builtin_amdgcn_readfirstlane(xrow[t0 + u]);

    float4 ka[8], kb[8];
    float vv[8];
#pragma unroll
    for (int u = 0; u < 8; ++u) {
      const int base = tk[u] * H;
      ka[u] = *(const float4*)(&Kt[base + c8]);
      kb[u] = *(const float4*)(&Kt[base + c8 + 4]);
      vv[u] = Vt[base + r];
    }

    // chunk-pair Gram scalars (uniform broadcast ds_reads)
    float g[8][8];
#pragma unroll
    for (int s = 0; s < 8; ++s)
#pragma unroll
      for (int t = s + 1; t < 8; ++t) g[s][t] = Gl[tk[s] * VOCAB + tk[t]];

    // 8 independent pre-predictions vs M_pre
    float w[8];
#pragma unroll
    for (int u = 0; u < 8; ++u) {
      float pa = fmaf(ka[u].x, M[0], fmaf(ka[u].y, M[1], fmaf(ka[u].z, M[2], ka[u].w * M[3])));
      float pb = fmaf(kb[u].x, M[4], fmaf(kb[u].y, M[5], fmaf(kb[u].z, M[6], kb[u].w * M[7])));
      float p = pa + pb;
      p = dpp_add<0xB1>(p);
      p = dpp_add<0x4E>(p);
      p = dpp_add<0x141>(p);
      w[u] = vv[u] - p;
    }

    // triangular solve: after this, w[u] == dl_u
#pragma unroll
    for (int s = 0; s < 8; ++s) {
#pragma unroll
      for (int t = s + 1; t < 8; ++t) w[t] = fmaf(-w[s], g[s][t], w[t]);
    }

    // rank-8 update (all independent)
#pragma unroll
    for (int u = 0; u < 8; ++u) {
      const float d = w[u];
      M[0] = fmaf(d, ka[u].x, M[0]); M[1] = fmaf(d, ka[u].y, M[1]);
      M[2] = fmaf(d, ka[u].z, M[2]); M[3] = fmaf(d, ka[u].w, M[3]);
      M[4] = fmaf(d, kb[u].x, M[4]); M[5] = fmaf(d, kb[u].y, M[5]);
      M[6] = fmaf(d, kb[u].z, M[6]); M[7] = fmaf(d, kb[u].w, M[7]);
    }
  }

  float* mp = Mout + ((size_t)bb * H + r) * H + c8;
  float4 a; a.x = M[0]; a.y = M[1]; a.z = M[2]; a.w = M[3];
  float4 b; b.x = M[4]; b.y = M[5]; b.z = M[6]; b.w = M[7];
  *(float4*)mp = a;
  *(float4*)(mp + 4) = b;
}

// ---------------- Kernel C: attention + readout ----------------
__global__ __launch_bounds__(64) void k_final(
    const int* __restrict__ x, const float* __restrict__ Mws, const float* __restrict__ qtab,
    const float* __restrict__ Wout, const float* __restrict__ bout, float* __restrict__ out)
{
  const int b = blockIdx.x;
  const int i = threadIdx.x;
  __shared__ float Ml[H * 65];
  __shared__ float qs[H];
  __shared__ float attns[H];
  __shared__ float rcs[H];

  const float* Mg = Mws + (size_t)b * H * H;
#pragma unroll
  for (int j4 = 0; j4 < H; j4 += 4) {
    const float4 v = *(const float4*)(Mg + i * H + j4);
    Ml[i * 65 + j4 + 0] = v.x;
    Ml[i * 65 + j4 + 1] = v.y;
    Ml[i * 65 + j4 + 2] = v.z;
    Ml[i * 65 + j4 + 3] = v.w;
  }
  const int tok = x[b * SL + (SL - 1)];
  qs[i] = qtab[tok * H + i];
  __syncthreads();

  float acc = 0.f;
#pragma unroll
  for (int j = 0; j < H; ++j) acc = fmaf(Ml[j * 65 + i], qs[j], acc);
  const float sc = acc * 0.125f;

  float mx = sc;
#pragma unroll
  for (int m = 1; m < 64; m <<= 1) mx = fmaxf(mx, __shfl_xor(mx, m));
  const float e = expf(sc - mx);
  float ssum = e;
#pragma unroll
  for (int m = 1; m < 64; m <<= 1) ssum += __shfl_xor(ssum, m);
  attns[i] = e / ssum;
  __syncthreads();

  float cx = 0.f;
#pragma unroll
  for (int jj = 0; jj < H; ++jj) cx = fmaf(attns[jj], Ml[i * 65 + jj], cx);
  rcs[i] = fmaxf(cx, 0.f);
  __syncthreads();

  float o = bout[i];
#pragma unroll
  for (int j = 0; j < H; ++j) o = fmaf(Wout[i * H + j], rcs[j], o);
  out[b * VOCAB + i] = o;
}

extern "C" void kernel_launch(void* const* d_in, const int* in_sizes, int n_in,
                              void* d_out, int out_size, void* d_ws, size_t ws_size,
                              hipStream_t stream) {
  const int*   x     = (const int*)d_in[0];
  const float* embed = (const float*)d_in[1];
  const float* w1    = (const float*)d_in[2];
  const float* b1    = (const float*)d_in[3];
  const float* w2    = (const float*)d_in[4];
  const float* b2    = (const float*)d_in[5];
  const float* ln_g  = (const float*)d_in[6];
  const float* ln_b  = (const float*)d_in[7];
  const float* Wk    = (const float*)d_in[8];
  const float* Wv    = (const float*)d_in[9];
  const float* Wq    = (const float*)d_in[10];
  const float* Wout  = (const float*)d_in[11];
  const float* bout  = (const float*)d_in[12];

  float* ws   = (float*)d_ws;
  float* Ktab = ws;                 // 4096
  float* Vtab = ws + 4096;          // 4096
  float* qtab = ws + 8192;          // 4096
  float* Gm   = ws + 12288;         // 4096
  float* Mws  = ws + 16384;         // 128*4096

  k_tables<<<dim3(VOCAB), dim3(H), 0, stream>>>(embed, w1, b1, w2, b2, ln_g, ln_b,
                                                Wk, Wv, Wq, Ktab, Vtab, qtab);
  k_gram<<<dim3(VOCAB), dim3(H), 0, stream>>>(Ktab, Gm);
  k_scan<<<dim3(2 * NB), dim3(256), 0, stream>>>(x, Ktab, Vtab, Gm, Mws);
  k_final<<<dim3(NB), dim3(H), 0, stream>>>(x, Mws, qtab, Wout, bout, (float*)d_out);
}

// Round 4
// 248.165 us; speedup vs baseline: 1.3347x; 1.3347x over previous
//
#include <hip/hip_runtime.h>
#include <hip/hip_bf16.h>

#define VOCAB 64
#define H 64
#define NB 128
#define SL 2048
#define NCH (SL / 4)  // 512 chunks of 4 tokens

// ---------------- Kernel A: per-token tables ----------------
__global__ __launch_bounds__(64) void k_tables(
    const float* __restrict__ embed, const float* __restrict__ w1, const float* __restrict__ b1,
    const float* __restrict__ w2, const float* __restrict__ b2,
    const float* __restrict__ ln_g, const float* __restrict__ ln_b,
    const float* __restrict__ Wk, const float* __restrict__ Wv, const float* __restrict__ Wq,
    float* __restrict__ Ktab, float* __restrict__ Vtab, float* __restrict__ qtab)
{
  const int t = blockIdx.x;
  const int i = threadIdx.x;
  __shared__ float h0s[H];
  __shared__ float ff1s[2 * H];
  __shared__ float hs[H];

  h0s[i] = embed[t * H + i];
  __syncthreads();

  const float4* w1v = (const float4*)w1;
  float a0 = b1[i], a1 = b1[i + H];
#pragma unroll
  for (int j4 = 0; j4 < 16; ++j4) {
    const float4 hv = *(const float4*)&h0s[j4 * 4];
    const float4 wa = w1v[i * 16 + j4];
    const float4 wb = w1v[(i + H) * 16 + j4];
    a0 = fmaf(wa.x, hv.x, fmaf(wa.y, hv.y, fmaf(wa.z, hv.z, fmaf(wa.w, hv.w, a0))));
    a1 = fmaf(wb.x, hv.x, fmaf(wb.y, hv.y, fmaf(wb.z, hv.z, fmaf(wb.w, hv.w, a1))));
  }
  ff1s[i] = fmaxf(a0, 0.f);
  ff1s[i + H] = fmaxf(a1, 0.f);
  __syncthreads();

  const float4* w2v = (const float4*)w2;
  float z = h0s[i] + b2[i];
#pragma unroll
  for (int o4 = 0; o4 < 32; ++o4) {
    const float4 fv = *(const float4*)&ff1s[o4 * 4];
    const float4 wv = w2v[i * 32 + o4];
    z = fmaf(wv.x, fv.x, fmaf(wv.y, fv.y, fmaf(wv.z, fv.z, fmaf(wv.w, fv.w, z))));
  }

  float s = z;
#pragma unroll
  for (int m = 1; m < 64; m <<= 1) s += __shfl_xor(s, m);
  const float mu = s * (1.f / 64.f);
  const float d = z - mu;
  float s2 = d * d;
#pragma unroll
  for (int m = 1; m < 64; m <<= 1) s2 += __shfl_xor(s2, m);
  const float var = s2 * (1.f / 64.f);
  const float hv2 = d * rsqrtf(var + 1e-5f) * ln_g[i] + ln_b[i];
  hs[i] = hv2;
  __syncthreads();

  const float4* wkv = (const float4*)Wk;
  const float4* wvv = (const float4*)Wv;
  const float4* wqv = (const float4*)Wq;
  float kk = 0.f, vv = 0.f, qq = 0.f;
#pragma unroll
  for (int j4 = 0; j4 < 16; ++j4) {
    const float4 hj = *(const float4*)&hs[j4 * 4];
    const float4 ak = wkv[i * 16 + j4];
    const float4 av = wvv[i * 16 + j4];
    const float4 aq = wqv[i * 16 + j4];
    kk = fmaf(ak.x, hj.x, fmaf(ak.y, hj.y, fmaf(ak.z, hj.z, fmaf(ak.w, hj.w, kk))));
    vv = fmaf(av.x, hj.x, fmaf(av.y, hj.y, fmaf(av.z, hj.z, fmaf(av.w, hj.w, vv))));
    qq = fmaf(aq.x, hj.x, fmaf(aq.y, hj.y, fmaf(aq.z, hj.z, fmaf(aq.w, hj.w, qq))));
  }
  float n2 = kk * kk;
#pragma unroll
  for (int m = 1; m < 64; m <<= 1) n2 += __shfl_xor(n2, m);
  const float inv = 1.f / fmaxf(sqrtf(n2), 1e-12f);
  Ktab[t * H + i] = kk * inv;
  Vtab[t * H + i] = vv;
  qtab[t * H + i] = qq;
}

// ---------------- Kernel B: pipelined chunked delta-rule scan ----------------
template <int CTRL>
__device__ __forceinline__ float dpp_add(float x) {
  int y = __builtin_amdgcn_update_dpp(0, __float_as_int(x), CTRL, 0xF, 0xF, false);
  return x + __int_as_float(y);
}
__device__ __forceinline__ float red8(float p) {
  p = dpp_add<0xB1>(p);   // xor1 (quad_perm)
  p = dpp_add<0x4E>(p);   // xor2 (quad_perm)
  p = dpp_add<0x141>(p);  // 8-lane half-row mirror
  return p;
}

__global__ __launch_bounds__(256) void k_scan(
    const int* __restrict__ x, const float* __restrict__ Ktab, const float* __restrict__ Vtab,
    float* __restrict__ Mout)
{
  const int bb = blockIdx.x >> 1;
  const int half = blockIdx.x & 1;
  const int tid = threadIdx.x;

  __shared__ float Kt[VOCAB * H];
  __shared__ float Vt[VOCAB * H];
  __shared__ float Gl[VOCAB * VOCAB];
  __shared__ int4 xs4[NCH + 2];

  // stage K/V tables + x row (coalesced)
#pragma unroll
  for (int u = 0; u < 4; ++u) {
    ((float4*)Kt)[u * 256 + tid] = ((const float4*)Ktab)[u * 256 + tid];
    ((float4*)Vt)[u * 256 + tid] = ((const float4*)Vtab)[u * 256 + tid];
  }
  const int4* gx4 = (const int4*)(x + bb * SL);
  xs4[tid] = gx4[tid];
  xs4[tid + 256] = gx4[tid + 256];
  if (tid < 2) xs4[NCH + tid] = make_int4(0, 0, 0, 0);
  __syncthreads();

  // in-block Gram: thread computes Gl[a][b0..b0+15], a = tid>>2, b0 = (tid&3)*16
  {
    const int a = tid >> 2;
    const int b0 = (tid & 3) * 16;
    float4 ra[16];
#pragma unroll
    for (int q = 0; q < 16; ++q) ra[q] = *(const float4*)&Kt[a * H + q * 4];
#pragma unroll
    for (int j = 0; j < 16; ++j) {
      const int b = b0 + j;
      float acc = 0.f;
#pragma unroll
      for (int q = 0; q < 16; ++q) {
        const float4 rb = *(const float4*)&Kt[b * H + q * 4];
        acc = fmaf(ra[q].x, rb.x, fmaf(ra[q].y, rb.y, fmaf(ra[q].z, rb.z, fmaf(ra[q].w, rb.w, acc))));
      }
      Gl[a * VOCAB + b] = acc;
    }
  }
  __syncthreads();

  const int r = half * 32 + (tid >> 3);
  const int c8 = (tid & 7) * 8;

  float M[8] = {0.f, 0.f, 0.f, 0.f, 0.f, 0.f, 0.f, 0.f};
  float4 kaA[4], kbA[4], kaB[4], kbB[4];
  float vvA[4], vvB[4];
  float gA[6], gB[6];
  int4 tvA, tvB;

#define GATHER(ka, kb, vv, g, tv)                                              \
  {                                                                            \
    const int b0_ = tv.x * H, b1_ = tv.y * H, b2_ = tv.z * H, b3_ = tv.w * H;  \
    ka[0] = *(const float4*)&Kt[b0_ + c8]; kb[0] = *(const float4*)&Kt[b0_ + c8 + 4]; \
    ka[1] = *(const float4*)&Kt[b1_ + c8]; kb[1] = *(const float4*)&Kt[b1_ + c8 + 4]; \
    ka[2] = *(const float4*)&Kt[b2_ + c8]; kb[2] = *(const float4*)&Kt[b2_ + c8 + 4]; \
    ka[3] = *(const float4*)&Kt[b3_ + c8]; kb[3] = *(const float4*)&Kt[b3_ + c8 + 4]; \
    vv[0] = Vt[b0_ + r]; vv[1] = Vt[b1_ + r];                                  \
    vv[2] = Vt[b2_ + r]; vv[3] = Vt[b3_ + r];                                  \
    g[0] = Gl[tv.x * VOCAB + tv.y]; g[1] = Gl[tv.x * VOCAB + tv.z];            \
    g[2] = Gl[tv.x * VOCAB + tv.w]; g[3] = Gl[tv.y * VOCAB + tv.z];            \
    g[4] = Gl[tv.y * VOCAB + tv.w]; g[5] = Gl[tv.z * VOCAB + tv.w];            \
  }

#define COMPUTE(ka, kb, vv, g)                                                 \
  {                                                                            \
    float p0 = fmaf(ka[0].x, M[0], fmaf(ka[0].y, M[1], fmaf(ka[0].z, M[2], ka[0].w * M[3]))) + \
               fmaf(kb[0].x, M[4], fmaf(kb[0].y, M[5], fmaf(kb[0].z, M[6], kb[0].w * M[7])));  \
    float p1 = fmaf(ka[1].x, M[0], fmaf(ka[1].y, M[1], fmaf(ka[1].z, M[2], ka[1].w * M[3]))) + \
               fmaf(kb[1].x, M[4], fmaf(kb[1].y, M[5], fmaf(kb[1].z, M[6], kb[1].w * M[7])));  \
    float p2 = fmaf(ka[2].x, M[0], fmaf(ka[2].y, M[1], fmaf(ka[2].z, M[2], ka[2].w * M[3]))) + \
               fmaf(kb[2].x, M[4], fmaf(kb[2].y, M[5], fmaf(kb[2].z, M[6], kb[2].w * M[7])));  \
    float p3 = fmaf(ka[3].x, M[0], fmaf(ka[3].y, M[1], fmaf(ka[3].z, M[2], ka[3].w * M[3]))) + \
               fmaf(kb[3].x, M[4], fmaf(kb[3].y, M[5], fmaf(kb[3].z, M[6], kb[3].w * M[7])));  \
    p0 = red8(p0); p1 = red8(p1); p2 = red8(p2); p3 = red8(p3);                \
    float w0 = vv[0] - p0, w1 = vv[1] - p1, w2 = vv[2] - p2, w3 = vv[3] - p3;  \
    w1 = fmaf(-w0, g[0], w1); w2 = fmaf(-w0, g[1], w2); w3 = fmaf(-w0, g[2], w3); \
    w2 = fmaf(-w1, g[3], w2); w3 = fmaf(-w1, g[4], w3);                        \
    w3 = fmaf(-w2, g[5], w3);                                                  \
    M[0] = fmaf(w0, ka[0].x, M[0]); M[1] = fmaf(w0, ka[0].y, M[1]);            \
    M[2] = fmaf(w0, ka[0].z, M[2]); M[3] = fmaf(w0, ka[0].w, M[3]);            \
    M[4] = fmaf(w0, kb[0].x, M[4]); M[5] = fmaf(w0, kb[0].y, M[5]);            \
    M[6] = fmaf(w0, kb[0].z, M[6]); M[7] = fmaf(w0, kb[0].w, M[7]);            \
    M[0] = fmaf(w1, ka[1].x, M[0]); M[1] = fmaf(w1, ka[1].y, M[1]);            \
    M[2] = fmaf(w1, ka[1].z, M[2]); M[3] = fmaf(w1, ka[1].w, M[3]);            \
    M[4] = fmaf(w1, kb[1].x, M[4]); M[5] = fmaf(w1, kb[1].y, M[5]);            \
    M[6] = fmaf(w1, kb[1].z, M[6]); M[7] = fmaf(w1, kb[1].w, M[7]);            \
    M[0] = fmaf(w2, ka[2].x, M[0]); M[1] = fmaf(w2, ka[2].y, M[1]);            \
    M[2] = fmaf(w2, ka[2].z, M[2]); M[3] = fmaf(w2, ka[2].w, M[3]);            \
    M[4] = fmaf(w2, kb[2].x, M[4]); M[5] = fmaf(w2, kb[2].y, M[5]);            \
    M[6] = fmaf(w2, kb[2].z, M[6]); M[7] = fmaf(w2, kb[2].w, M[7]);            \
    M[0] = fmaf(w3, ka[3].x, M[0]); M[1] = fmaf(w3, ka[3].y, M[1]);            \
    M[2] = fmaf(w3, ka[3].z, M[2]); M[3] = fmaf(w3, ka[3].w, M[3]);            \
    M[4] = fmaf(w3, kb[3].x, M[4]); M[5] = fmaf(w3, kb[3].y, M[5]);            \
    M[6] = fmaf(w3, kb[3].z, M[6]); M[7] = fmaf(w3, kb[3].w, M[7]);            \
  }

  // pipeline preamble: tokens for chunks 0,1; gathers for chunk 0
  tvA = xs4[0];
  tvB = xs4[1];
  GATHER(kaA, kbA, vvA, gA, tvA);

#pragma unroll 1
  for (int n = 0; n < NCH; n += 2) {
    // slot n (even): prefetch tokens n+2; gather chunk n+1; compute chunk n
    tvA = xs4[n + 2];
    GATHER(kaB, kbB, vvB, gB, tvB);
    COMPUTE(kaA, kbA, vvA, gA);
    // slot n+1 (odd): prefetch tokens n+3; gather chunk n+2; compute chunk n+1
    tvB = xs4[n + 3];
    GATHER(kaA, kbA, vvA, gA, tvA);
    COMPUTE(kaB, kbB, vvB, gB);
  }

  float* mp = Mout + ((size_t)bb * H + r) * H + c8;
  float4 a; a.x = M[0]; a.y = M[1]; a.z = M[2]; a.w = M[3];
  float4 b; b.x = M[4]; b.y = M[5]; b.z = M[6]; b.w = M[7];
  *(float4*)mp = a;
  *(float4*)(mp + 4) = b;
#undef GATHER
#undef COMPUTE
}

// ---------------- Kernel C: attention + readout ----------------
__global__ __launch_bounds__(64) void k_final(
    const int* __restrict__ x, const float* __restrict__ Mws, const float* __restrict__ qtab,
    const float* __restrict__ Wout, const float* __restrict__ bout, float* __restrict__ out)
{
  const int b = blockIdx.x;
  const int i = threadIdx.x;
  __shared__ float Ml[H * 65];
  __shared__ float qs[H];
  __shared__ float attns[H];
  __shared__ float rcs[H];

  const float* Mg = Mws + (size_t)b * H * H;
#pragma unroll
  for (int j4 = 0; j4 < H; j4 += 4) {
    const float4 v = *(const float4*)(Mg + i * H + j4);
    Ml[i * 65 + j4 + 0] = v.x;
    Ml[i * 65 + j4 + 1] = v.y;
    Ml[i * 65 + j4 + 2] = v.z;
    Ml[i * 65 + j4 + 3] = v.w;
  }
  const int tok = x[b * SL + (SL - 1)];
  qs[i] = qtab[tok * H + i];
  __syncthreads();

  float acc = 0.f;
#pragma unroll
  for (int j = 0; j < H; ++j) acc = fmaf(Ml[j * 65 + i], qs[j], acc);
  const float sc = acc * 0.125f;

  float mx = sc;
#pragma unroll
  for (int m = 1; m < 64; m <<= 1) mx = fmaxf(mx, __shfl_xor(mx, m));
  const float e = expf(sc - mx);
  float ssum = e;
#pragma unroll
  for (int m = 1; m < 64; m <<= 1) ssum += __shfl_xor(ssum, m);
  attns[i] = e / ssum;
  __syncthreads();

  float cx = 0.f;
#pragma unroll
  for (int jj = 0; jj < H; ++jj) cx = fmaf(attns[jj], Ml[i * 65 + jj], cx);
  rcs[i] = fmaxf(cx, 0.f);
  __syncthreads();

  float o = bout[i];
#pragma unroll
  for (int j = 0; j < H; ++j) o = fmaf(Wout[i * H + j], rcs[j], o);
  out[b * VOCAB + i] = o;
}

extern "C" void kernel_launch(void* const* d_in, const int* in_sizes, int n_in,
                              void* d_out, int out_size, void* d_ws, size_t ws_size,
                              hipStream_t stream) {
  const int*   x     = (const int*)d_in[0];
  const float* embed = (const float*)d_in[1];
  const float* w1    = (const float*)d_in[2];
  const float* b1    = (const float*)d_in[3];
  const float* w2    = (const float*)d_in[4];
  const float* b2    = (const float*)d_in[5];
  const float* ln_g  = (const float*)d_in[6];
  const float* ln_b  = (const float*)d_in[7];
  const float* Wk    = (const float*)d_in[8];
  const float* Wv    = (const float*)d_in[9];
  const float* Wq    = (const float*)d_in[10];
  const float* Wout  = (const float*)d_in[11];
  const float* bout  = (const float*)d_in[12];

  float* ws   = (float*)d_ws;
  float* Ktab = ws;                 // 4096
  float* Vtab = ws + 4096;          // 4096
  float* qtab = ws + 8192;          // 4096
  float* Mws  = ws + 12288;         // 128*4096

  k_tables<<<dim3(VOCAB), dim3(H), 0, stream>>>(embed, w1, b1, w2, b2, ln_g, ln_b,
                                                Wk, Wv, Wq, Ktab, Vtab, qtab);
  k_scan<<<dim3(2 * NB), dim3(256), 0, stream>>>(x, Ktab, Vtab, Mws);
  k_final<<<dim3(NB), dim3(64), 0, stream>>>(x, Mws, qtab, Wout, bout, (float*)d_out);
}

// Round 5
// 245.026 us; speedup vs baseline: 1.3518x; 1.0128x over previous
//
#include <hip/hip_runtime.h>
#include <hip/hip_bf16.h>

#define VOCAB 64
#define H 64
#define NB 128
#define SL 2048
#define NCH (SL / 4)  // 512 chunks of 4 tokens

typedef __attribute__((ext_vector_type(2))) float f32x2;

// ---------------- Kernel A: per-token tables ----------------
__global__ __launch_bounds__(64) void k_tables(
    const float* __restrict__ embed, const float* __restrict__ w1, const float* __restrict__ b1,
    const float* __restrict__ w2, const float* __restrict__ b2,
    const float* __restrict__ ln_g, const float* __restrict__ ln_b,
    const float* __restrict__ Wk, const float* __restrict__ Wv, const float* __restrict__ Wq,
    float* __restrict__ Ktab, float* __restrict__ Vtab, float* __restrict__ qtab)
{
  const int t = blockIdx.x;
  const int i = threadIdx.x;
  __shared__ float h0s[H];
  __shared__ float ff1s[2 * H];
  __shared__ float hs[H];

  h0s[i] = embed[t * H + i];
  __syncthreads();

  const float4* w1v = (const float4*)w1;
  float a0 = b1[i], a1 = b1[i + H];
#pragma unroll
  for (int j4 = 0; j4 < 16; ++j4) {
    const float4 hv = *(const float4*)&h0s[j4 * 4];
    const float4 wa = w1v[i * 16 + j4];
    const float4 wb = w1v[(i + H) * 16 + j4];
    a0 = fmaf(wa.x, hv.x, fmaf(wa.y, hv.y, fmaf(wa.z, hv.z, fmaf(wa.w, hv.w, a0))));
    a1 = fmaf(wb.x, hv.x, fmaf(wb.y, hv.y, fmaf(wb.z, hv.z, fmaf(wb.w, hv.w, a1))));
  }
  ff1s[i] = fmaxf(a0, 0.f);
  ff1s[i + H] = fmaxf(a1, 0.f);
  __syncthreads();

  const float4* w2v = (const float4*)w2;
  float z = h0s[i] + b2[i];
#pragma unroll
  for (int o4 = 0; o4 < 32; ++o4) {
    const float4 fv = *(const float4*)&ff1s[o4 * 4];
    const float4 wv = w2v[i * 32 + o4];
    z = fmaf(wv.x, fv.x, fmaf(wv.y, fv.y, fmaf(wv.z, fv.z, fmaf(wv.w, fv.w, z))));
  }

  float s = z;
#pragma unroll
  for (int m = 1; m < 64; m <<= 1) s += __shfl_xor(s, m);
  const float mu = s * (1.f / 64.f);
  const float d = z - mu;
  float s2 = d * d;
#pragma unroll
  for (int m = 1; m < 64; m <<= 1) s2 += __shfl_xor(s2, m);
  const float var = s2 * (1.f / 64.f);
  const float hv2 = d * rsqrtf(var + 1e-5f) * ln_g[i] + ln_b[i];
  hs[i] = hv2;
  __syncthreads();

  const float4* wkv = (const float4*)Wk;
  const float4* wvv = (const float4*)Wv;
  const float4* wqv = (const float4*)Wq;
  float kk = 0.f, vv = 0.f, qq = 0.f;
#pragma unroll
  for (int j4 = 0; j4 < 16; ++j4) {
    const float4 hj = *(const float4*)&hs[j4 * 4];
    const float4 ak = wkv[i * 16 + j4];
    const float4 av = wvv[i * 16 + j4];
    const float4 aq = wqv[i * 16 + j4];
    kk = fmaf(ak.x, hj.x, fmaf(ak.y, hj.y, fmaf(ak.z, hj.z, fmaf(ak.w, hj.w, kk))));
    vv = fmaf(av.x, hj.x, fmaf(av.y, hj.y, fmaf(av.z, hj.z, fmaf(av.w, hj.w, vv))));
    qq = fmaf(aq.x, hj.x, fmaf(aq.y, hj.y, fmaf(aq.z, hj.z, fmaf(aq.w, hj.w, qq))));
  }
  float n2 = kk * kk;
#pragma unroll
  for (int m = 1; m < 64; m <<= 1) n2 += __shfl_xor(n2, m);
  const float inv = 1.f / fmaxf(sqrtf(n2), 1e-12f);
  Ktab[t * H + i] = kk * inv;
  Vtab[t * H + i] = vv;
  qtab[t * H + i] = qq;
}

// ---------------- Kernel B: pipelined chunked delta-rule scan ----------------
// packed-f32 FMA (VOP3P): d = a*b + c on both halves
__device__ __forceinline__ f32x2 pk_fma(f32x2 a, f32x2 b, f32x2 c) {
  f32x2 d;
  asm("v_pk_fma_f32 %0, %1, %2, %3" : "=v"(d) : "v"(a), "v"(b), "v"(c));
  return d;
}

template <int CTRL>
__device__ __forceinline__ float dpp_add(float x) {
  // old = src: all lanes valid under these xor patterns -> no zero-mov needed
  int xi = __float_as_int(x);
  int y = __builtin_amdgcn_update_dpp(xi, xi, CTRL, 0xF, 0xF, false);
  return x + __int_as_float(y);
}
__device__ __forceinline__ float red8(float p) {
  p = dpp_add<0xB1>(p);   // xor1 (quad_perm [1,0,3,2])
  p = dpp_add<0x4E>(p);   // xor2 (quad_perm [2,3,0,1])
  p = dpp_add<0x141>(p);  // 8-lane half-row mirror (acts as xor4 after quads uniform)
  return p;
}

__global__ __launch_bounds__(256) void k_scan(
    const int* __restrict__ x, const float* __restrict__ Ktab, const float* __restrict__ Vtab,
    float* __restrict__ Mout)
{
  const int bb = blockIdx.x >> 1;
  const int half = blockIdx.x & 1;
  const int tid = threadIdx.x;

  __shared__ float Kt[VOCAB * H];        // unpadded: scan k-slice reads (2-way max)
  __shared__ float Ktp[VOCAB * 68];      // padded: gram build (conflict-free)
  __shared__ float Vt[VOCAB * H];
  __shared__ float Gl[VOCAB * 68];       // padded: conflict-free writes
  __shared__ int4 xs4[NCH + 2];

  // stage tables + x row (coalesced)
#pragma unroll
  for (int u = 0; u < 4; ++u) {
    const int f4i = u * 256 + tid;           // 0..1023
    const float4 kv = ((const float4*)Ktab)[f4i];
    const float4 vv = ((const float4*)Vtab)[f4i];
    ((float4*)Kt)[f4i] = kv;
    ((float4*)Vt)[f4i] = vv;
    const int row = f4i >> 4, c4 = f4i & 15;
    *(float4*)&Ktp[row * 68 + c4 * 4] = kv;
  }
  const int4* gx4 = (const int4*)(x + bb * SL);
  xs4[tid] = gx4[tid];
  xs4[tid + 256] = gx4[tid + 256];
  if (tid < 2) xs4[NCH + tid] = make_int4(0, 0, 0, 0);
  __syncthreads();

  // in-block Gram from padded Kt: thread (a = tid>>2, bq = tid&3), b = bq + 4j
  {
    const int a = tid >> 2;
    const int bq = tid & 3;
    float4 ra[16];
#pragma unroll
    for (int q = 0; q < 16; ++q) ra[q] = *(const float4*)&Ktp[a * 68 + q * 4];
#pragma unroll
    for (int j = 0; j < 16; ++j) {
      const int b = bq + 4 * j;
      float acc = 0.f;
#pragma unroll
      for (int q = 0; q < 16; ++q) {
        const float4 rb = *(const float4*)&Ktp[b * 68 + q * 4];
        acc = fmaf(ra[q].x, rb.x, fmaf(ra[q].y, rb.y, fmaf(ra[q].z, rb.z, fmaf(ra[q].w, rb.w, acc))));
      }
      Gl[a * 68 + b] = acc;
    }
  }
  __syncthreads();

  const int r = half * 32 + (tid >> 3);
  const int c8 = (tid & 7) * 8;

  f32x2 M2[4];
#pragma unroll
  for (int i = 0; i < 4; ++i) M2[i] = (f32x2)(0.f);

  f32x2 kA[16], kB[16];   // 4 tokens x 4 col-pairs
  float vvA[4], vvB[4];
  float gA[6], gB[6];
  int4 tvA, tvB;

#define GATHER(kk, vv, g, tv)                                                  \
  {                                                                            \
    const int b0_ = tv.x * H, b1_ = tv.y * H, b2_ = tv.z * H, b3_ = tv.w * H;  \
    *(float4*)&kk[0]  = *(const float4*)&Kt[b0_ + c8];                         \
    *(float4*)&kk[2]  = *(const float4*)&Kt[b0_ + c8 + 4];                     \
    *(float4*)&kk[4]  = *(const float4*)&Kt[b1_ + c8];                         \
    *(float4*)&kk[6]  = *(const float4*)&Kt[b1_ + c8 + 4];                     \
    *(float4*)&kk[8]  = *(const float4*)&Kt[b2_ + c8];                         \
    *(float4*)&kk[10] = *(const float4*)&Kt[b2_ + c8 + 4];                     \
    *(float4*)&kk[12] = *(const float4*)&Kt[b3_ + c8];                         \
    *(float4*)&kk[14] = *(const float4*)&Kt[b3_ + c8 + 4];                     \
    vv[0] = Vt[b0_ + r]; vv[1] = Vt[b1_ + r];                                  \
    vv[2] = Vt[b2_ + r]; vv[3] = Vt[b3_ + r];                                  \
    g[0] = Gl[tv.x * 68 + tv.y]; g[1] = Gl[tv.x * 68 + tv.z];                  \
    g[2] = Gl[tv.x * 68 + tv.w]; g[3] = Gl[tv.y * 68 + tv.z];                  \
    g[4] = Gl[tv.y * 68 + tv.w]; g[5] = Gl[tv.z * 68 + tv.w];                  \
  }

#define COMPUTE(kk, vv, g)                                                     \
  {                                                                            \
    f32x2 pp0 = pk_fma(kk[3],  M2[3], (f32x2)(0.f));                           \
    f32x2 pp1 = pk_fma(kk[7],  M2[3], (f32x2)(0.f));                           \
    f32x2 pp2 = pk_fma(kk[11], M2[3], (f32x2)(0.f));                           \
    f32x2 pp3 = pk_fma(kk[15], M2[3], (f32x2)(0.f));                           \
    pp0 = pk_fma(kk[2],  M2[2], pp0); pp0 = pk_fma(kk[1],  M2[1], pp0);        \
    pp0 = pk_fma(kk[0],  M2[0], pp0);                                          \
    pp1 = pk_fma(kk[6],  M2[2], pp1); pp1 = pk_fma(kk[5],  M2[1], pp1);        \
    pp1 = pk_fma(kk[4],  M2[0], pp1);                                          \
    pp2 = pk_fma(kk[10], M2[2], pp2); pp2 = pk_fma(kk[9],  M2[1], pp2);        \
    pp2 = pk_fma(kk[8],  M2[0], pp2);                                          \
    pp3 = pk_fma(kk[14], M2[2], pp3); pp3 = pk_fma(kk[13], M2[1], pp3);        \
    pp3 = pk_fma(kk[12], M2[0], pp3);                                          \
    float p0 = red8(pp0.x + pp0.y);                                            \
    float p1 = red8(pp1.x + pp1.y);                                            \
    float p2 = red8(pp2.x + pp2.y);                                            \
    float p3 = red8(pp3.x + pp3.y);                                            \
    float w0 = vv[0] - p0, w1 = vv[1] - p1, w2 = vv[2] - p2, w3 = vv[3] - p3;  \
    w1 = fmaf(-w0, g[0], w1); w2 = fmaf(-w0, g[1], w2); w3 = fmaf(-w0, g[2], w3); \
    w2 = fmaf(-w1, g[3], w2); w3 = fmaf(-w1, g[4], w3);                        \
    w3 = fmaf(-w2, g[5], w3);                                                  \
    f32x2 wd0 = (f32x2)(w0), wd1 = (f32x2)(w1), wd2 = (f32x2)(w2), wd3 = (f32x2)(w3); \
    M2[0] = pk_fma(wd0, kk[0],  M2[0]); M2[1] = pk_fma(wd0, kk[1],  M2[1]);    \
    M2[2] = pk_fma(wd0, kk[2],  M2[2]); M2[3] = pk_fma(wd0, kk[3],  M2[3]);    \
    M2[0] = pk_fma(wd1, kk[4],  M2[0]); M2[1] = pk_fma(wd1, kk[5],  M2[1]);    \
    M2[2] = pk_fma(wd1, kk[6],  M2[2]); M2[3] = pk_fma(wd1, kk[7],  M2[3]);    \
    M2[0] = pk_fma(wd2, kk[8],  M2[0]); M2[1] = pk_fma(wd2, kk[9],  M2[1]);    \
    M2[2] = pk_fma(wd2, kk[10], M2[2]); M2[3] = pk_fma(wd2, kk[11], M2[3]);    \
    M2[0] = pk_fma(wd3, kk[12], M2[0]); M2[1] = pk_fma(wd3, kk[13], M2[1]);    \
    M2[2] = pk_fma(wd3, kk[14], M2[2]); M2[3] = pk_fma(wd3, kk[15], M2[3]);    \
  }

  // pipeline preamble: tokens for chunks 0,1; gathers for chunk 0
  tvA = xs4[0];
  tvB = xs4[1];
  GATHER(kA, vvA, gA, tvA);

#pragma unroll 1
  for (int n = 0; n < NCH; n += 2) {
    tvA = xs4[n + 2];
    GATHER(kB, vvB, gB, tvB);
    COMPUTE(kA, vvA, gA);
    tvB = xs4[n + 3];
    GATHER(kA, vvA, gA, tvA);
    COMPUTE(kB, vvB, gB);
  }

  float* mp = Mout + ((size_t)bb * H + r) * H + c8;
  *(float4*)mp = *(float4*)&M2[0];
  *(float4*)(mp + 4) = *(float4*)&M2[2];
#undef GATHER
#undef COMPUTE
}

// ---------------- Kernel C: attention + readout ----------------
__global__ __launch_bounds__(64) void k_final(
    const int* __restrict__ x, const float* __restrict__ Mws, const float* __restrict__ qtab,
    const float* __restrict__ Wout, const float* __restrict__ bout, float* __restrict__ out)
{
  const int b = blockIdx.x;
  const int i = threadIdx.x;
  __shared__ float Ml[H * 65];
  __shared__ float qs[H];
  __shared__ float attns[H];
  __shared__ float rcs[H];

  const float* Mg = Mws + (size_t)b * H * H;
#pragma unroll
  for (int j4 = 0; j4 < H; j4 += 4) {
    const float4 v = *(const float4*)(Mg + i * H + j4);
    Ml[i * 65 + j4 + 0] = v.x;
    Ml[i * 65 + j4 + 1] = v.y;
    Ml[i * 65 + j4 + 2] = v.z;
    Ml[i * 65 + j4 + 3] = v.w;
  }
  const int tok = x[b * SL + (SL - 1)];
  qs[i] = qtab[tok * H + i];
  __syncthreads();

  float acc = 0.f;
#pragma unroll
  for (int j = 0; j < H; ++j) acc = fmaf(Ml[j * 65 + i], qs[j], acc);
  const float sc = acc * 0.125f;

  float mx = sc;
#pragma unroll
  for (int m = 1; m < 64; m <<= 1) mx = fmaxf(mx, __shfl_xor(mx, m));
  const float e = expf(sc - mx);
  float ssum = e;
#pragma unroll
  for (int m = 1; m < 64; m <<= 1) ssum += __shfl_xor(ssum, m);
  attns[i] = e / ssum;
  __syncthreads();

  float cx = 0.f;
#pragma unroll
  for (int jj = 0; jj < H; ++jj) cx = fmaf(attns[jj], Ml[i * 65 + jj], cx);
  rcs[i] = fmaxf(cx, 0.f);
  __syncthreads();

  float o = bout[i];
#pragma unroll
  for (int j = 0; j < H; ++j) o = fmaf(Wout[i * H + j], rcs[j], o);
  out[b * VOCAB + i] = o;
}

extern "C" void kernel_launch(void* const* d_in, const int* in_sizes, int n_in,
                              void* d_out, int out_size, void* d_ws, size_t ws_size,
                              hipStream_t stream) {
  const int*   x     = (const int*)d_in[0];
  const float* embed = (const float*)d_in[1];
  const float* w1    = (const float*)d_in[2];
  const float* b1    = (const float*)d_in[3];
  const float* w2    = (const float*)d_in[4];
  const float* b2    = (const float*)d_in[5];
  const float* ln_g  = (const float*)d_in[6];
  const float* ln_b  = (const float*)d_in[7];
  const float* Wk    = (const float*)d_in[8];
  const float* Wv    = (const float*)d_in[9];
  const float* Wq    = (const float*)d_in[10];
  const float* Wout  = (const float*)d_in[11];
  const float* bout  = (const float*)d_in[12];

  float* ws   = (float*)d_ws;
  float* Ktab = ws;                 // 4096
  float* Vtab = ws + 4096;          // 4096
  float* qtab = ws + 8192;          // 4096
  float* Mws  = ws + 12288;         // 128*4096

  k_tables<<<dim3(VOCAB), dim3(H), 0, stream>>>(embed, w1, b1, w2, b2, ln_g, ln_b,
                                                Wk, Wv, Wq, Ktab, Vtab, qtab);
  k_scan<<<dim3(2 * NB), dim3(256), 0, stream>>>(x, Ktab, Vtab, Mws);
  k_final<<<dim3(NB), dim3(64), 0, stream>>>(x, Mws, qtab, Wout, bout, (float*)d_out);
}